// Round 1
// baseline (665.975 us; speedup 1.0000x reference)
//
#include <hip/hip_runtime.h>
#include <math.h>

// ---------------------------------------------------------------------------
// GAT network: 3 layers. N=50000 nodes, E=800000 edges, IN=128, H=2, D=128.
// Strategy: build CSR-by-dst once per call; per layer: fp32 tiled GEMM,
// el/er attention dots, then one-block-per-node online-softmax aggregation
// (no atomics in the heavy phase, coalesced 1KB feat[src] gathers).
// ---------------------------------------------------------------------------

#define NEG_ATTN 0.2f
#define NEG_ACT  0.01f

// ---------------- CSR build ----------------

__global__ void count_edges(const int* __restrict__ dst, int* __restrict__ counts, int E) {
    int e = blockIdx.x * blockDim.x + threadIdx.x;
    if (e < E) atomicAdd(&counts[dst[e]], 1);
}

// single-block scan: offsets[0]=0, offsets[i+1]=inclusive_prefix(counts,i)
__global__ void scan_offsets(const int* __restrict__ counts, int* __restrict__ offsets, int N) {
    const int PER = 16;
    __shared__ int tmp[1024];
    __shared__ int carry_sh;
    int t = threadIdx.x;
    if (t == 0) { carry_sh = 0; offsets[0] = 0; }
    __syncthreads();
    for (int base = 0; base < N; base += 1024 * PER) {
        int i0 = base + t * PER;
        int loc[PER];
        int sum = 0;
        #pragma unroll
        for (int j = 0; j < PER; ++j) {
            int i = i0 + j;
            int v = (i < N) ? counts[i] : 0;
            sum += v;
            loc[j] = sum;               // inclusive within thread
        }
        tmp[t] = sum;
        __syncthreads();
        for (int off = 1; off < 1024; off <<= 1) {
            int x = (t >= off) ? tmp[t - off] : 0;
            __syncthreads();
            tmp[t] += x;
            __syncthreads();
        }
        int excl = (t == 0) ? 0 : tmp[t - 1];
        int carry = carry_sh;
        #pragma unroll
        for (int j = 0; j < PER; ++j) {
            int i = i0 + j;
            if (i < N) offsets[i + 1] = carry + excl + loc[j];
        }
        __syncthreads();
        if (t == 0) carry_sh = carry + tmp[1023];
        __syncthreads();
    }
}

__global__ void scatter_edges(const int* __restrict__ src, const int* __restrict__ dst,
                              const int* __restrict__ offsets, int* __restrict__ cursor,
                              int* __restrict__ csr_src, int E) {
    int e = blockIdx.x * blockDim.x + threadIdx.x;
    if (e < E) {
        int d = dst[e];
        int pos = offsets[d] + atomicAdd(&cursor[d], 1);
        csr_src[pos] = src[e];
    }
}

// ---------------- fp32 tiled GEMM: C[M,Nw] = A[M,K] @ B[K,Nw] ----------------
// BM=BN=64, BK=32, 256 threads, 4x4 per thread. K % 32 == 0, Nw % 64 == 0.

__global__ __launch_bounds__(256) void gemm_tiled(
    const float* __restrict__ A, const float* __restrict__ B, float* __restrict__ C,
    int M, int K, int Nw)
{
    const int BM = 64, BN = 64, BK = 32;
    __shared__ float As[BM][BK + 4];   // stride 36: 16B-alignable, ~2-way bank dup (free)
    __shared__ float Bs[BK][BN];
    int tid = threadIdx.x;
    int tx = tid & 15, ty = tid >> 4;
    int bm = blockIdx.x * BM;
    int bn = blockIdx.y * BN;

    float acc[4][4] = {};

    int arow = tid >> 3;            // 0..31
    int acol = (tid & 7) * 4;       // 0..28
    int brow = tid >> 4;            // 0..15
    int bcol = (tid & 15) * 4;      // 0..60

    for (int k0 = 0; k0 < K; k0 += BK) {
        #pragma unroll
        for (int r = 0; r < 2; ++r) {
            int row = arow + r * 32;
            int grow = bm + row;
            if (grow >= M) grow = M - 1;     // clamp (store is guarded)
            float4 v = *reinterpret_cast<const float4*>(&A[(size_t)grow * K + k0 + acol]);
            *reinterpret_cast<float4*>(&As[row][acol]) = v;
        }
        #pragma unroll
        for (int r = 0; r < 2; ++r) {
            int row = brow + r * 16;
            float4 v = *reinterpret_cast<const float4*>(&B[(size_t)(k0 + row) * Nw + bn + bcol]);
            *reinterpret_cast<float4*>(&Bs[row][bcol]) = v;
        }
        __syncthreads();
        #pragma unroll
        for (int k = 0; k < BK; k += 4) {
            float4 a[4];
            float4 br[4];
            #pragma unroll
            for (int i = 0; i < 4; ++i) a[i] = *reinterpret_cast<const float4*>(&As[ty * 4 + i][k]);
            #pragma unroll
            for (int kk = 0; kk < 4; ++kk) br[kk] = *reinterpret_cast<const float4*>(&Bs[k + kk][tx * 4]);
            #pragma unroll
            for (int i = 0; i < 4; ++i) {
                float av[4] = {a[i].x, a[i].y, a[i].z, a[i].w};
                #pragma unroll
                for (int kk = 0; kk < 4; ++kk) {
                    acc[i][0] = fmaf(av[kk], br[kk].x, acc[i][0]);
                    acc[i][1] = fmaf(av[kk], br[kk].y, acc[i][1]);
                    acc[i][2] = fmaf(av[kk], br[kk].z, acc[i][2]);
                    acc[i][3] = fmaf(av[kk], br[kk].w, acc[i][3]);
                }
            }
        }
        __syncthreads();
    }

    #pragma unroll
    for (int i = 0; i < 4; ++i) {
        int gm = bm + ty * 4 + i;
        if (gm < M) {
            float4 v = make_float4(acc[i][0], acc[i][1], acc[i][2], acc[i][3]);
            *reinterpret_cast<float4*>(&C[(size_t)gm * Nw + bn + tx * 4]) = v;
        }
    }
}

// ---------------- el/er: per-(node,head) dots with al/ar ----------------
// block = 256 threads = 4 waves; wave w -> node blockIdx*2 + (w>>1), head w&1

__global__ __launch_bounds__(256) void compute_eler(
    const float* __restrict__ feat, const float* __restrict__ al, const float* __restrict__ ar,
    float* __restrict__ el, float* __restrict__ er, int N)
{
    int wv = threadIdx.x >> 6, lane = threadIdx.x & 63;
    int n = blockIdx.x * 2 + (wv >> 1);
    int h = wv & 1;
    if (n >= N) return;
    const float* f  = feat + (size_t)n * 256 + h * 128;
    const float* ap = al + h * 128;
    const float* rp = ar + h * 128;
    float f0 = f[lane], f1 = f[lane + 64];
    float pl = fmaf(f0, ap[lane], f1 * ap[lane + 64]);
    float pr = fmaf(f0, rp[lane], f1 * rp[lane + 64]);
    #pragma unroll
    for (int off = 32; off; off >>= 1) {
        pl += __shfl_down(pl, off);
        pr += __shfl_down(pr, off);
    }
    if (lane == 0) {
        el[(size_t)n * 2 + h] = pl;
        er[(size_t)n * 2 + h] = pr;
    }
}

// ---------------- per-node online-softmax aggregation (layers 0/1) ----------------
// one block (256 thr) per node; thread t -> (h = t>>7, d = t&127)

__global__ __launch_bounds__(256) void gat_aggregate(
    const float* __restrict__ feat, const float* __restrict__ el, const float* __restrict__ er,
    const int* __restrict__ offsets, const int* __restrict__ csr_src,
    const float* __restrict__ bias, float* __restrict__ out, int N, int activate)
{
    __shared__ float e_sh[64];
    __shared__ int   src_sh[32];
    int n = blockIdx.x;
    int t = threadIdx.x;
    int h = t >> 7;
    int start = offsets[n], end = offsets[n + 1];

    float m = -__builtin_inff();
    float s = 0.f, acc = 0.f;

    for (int base = start; base < end; base += 32) {
        int cnt = min(32, end - base);
        __syncthreads();
        if (t < cnt) src_sh[t] = csr_src[base + t];
        __syncthreads();
        if (t < 64) {
            int c = t & 31, hh = t >> 5;
            if (c < cnt) {
                float e = el[(size_t)src_sh[c] * 2 + hh] + er[(size_t)n * 2 + hh];
                e_sh[hh * 32 + c] = (e >= 0.f) ? e : NEG_ATTN * e;
            }
        }
        __syncthreads();
        for (int c = 0; c < cnt; ++c) {
            float e = e_sh[h * 32 + c];
            if (e > m) {                       // online softmax rescale
                float sc = __expf(m - e);
                s *= sc; acc *= sc; m = e;
            }
            float w = __expf(e - m);
            s += w;
            acc = fmaf(w, feat[(size_t)src_sh[c] * 256 + t], acc);
        }
    }

    float o = (s > 0.f) ? (acc / s) : 0.f;
    o += bias[t];
    if (activate) o = (o >= 0.f) ? o : NEG_ACT * o;
    out[(size_t)n * 256 + t] = o;
}

// ---------------- layer 2: feat2 = h2 @ W2 (K=256), then scalar softmax ----------------

__global__ __launch_bounds__(256) void gemv2(const float* __restrict__ h2, const float* __restrict__ W2,
                                             float* __restrict__ feat2, int N)
{
    int wv = threadIdx.x >> 6, lane = threadIdx.x & 63;
    int n = blockIdx.x * 4 + wv;
    if (n >= N) return;
    const float* row = h2 + (size_t)n * 256;
    float p = 0.f;
    #pragma unroll
    for (int i = 0; i < 4; ++i) p = fmaf(row[lane + 64 * i], W2[lane + 64 * i], p);
    #pragma unroll
    for (int off = 32; off; off >>= 1) p += __shfl_down(p, off);
    if (lane == 0) feat2[n] = p;
}

__global__ __launch_bounds__(256) void gat_aggregate2(
    const float* __restrict__ feat2, const float* __restrict__ al2, const float* __restrict__ ar2,
    const float* __restrict__ b2, const int* __restrict__ offsets, const int* __restrict__ csr_src,
    float* __restrict__ out, int N)
{
    int n = blockIdx.x * blockDim.x + threadIdx.x;
    if (n >= N) return;
    float alv = al2[0], arv = ar2[0];
    float ern = feat2[n] * arv;
    float m = -__builtin_inff();
    float s = 0.f, acc = 0.f;
    int end = offsets[n + 1];
    for (int p = offsets[n]; p < end; ++p) {
        int sn = csr_src[p];
        float f = feat2[sn];
        float e = fmaf(f, alv, ern);
        e = (e >= 0.f) ? e : NEG_ATTN * e;
        if (e > m) {
            float sc = __expf(m - e);
            s *= sc; acc *= sc; m = e;
        }
        float w = __expf(e - m);
        s += w;
        acc = fmaf(w, f, acc);
    }
    float o = (s > 0.f) ? (acc / s) : 0.f;
    out[n] = o + b2[0];
}

// ---------------------------------------------------------------------------

extern "C" void kernel_launch(void* const* d_in, const int* in_sizes, int n_in,
                              void* d_out, int out_size, void* d_ws, size_t ws_size,
                              hipStream_t stream)
{
    const float* features = (const float*)d_in[0];
    const int*   src      = (const int*)d_in[1];
    const int*   dst      = (const int*)d_in[2];
    const float* W0  = (const float*)d_in[3];
    const float* al0 = (const float*)d_in[4];
    const float* ar0 = (const float*)d_in[5];
    const float* b0  = (const float*)d_in[6];
    const float* W1  = (const float*)d_in[7];
    const float* al1 = (const float*)d_in[8];
    const float* ar1 = (const float*)d_in[9];
    const float* b1  = (const float*)d_in[10];
    const float* W2  = (const float*)d_in[11];
    const float* al2 = (const float*)d_in[12];
    const float* ar2 = (const float*)d_in[13];
    const float* b2  = (const float*)d_in[14];

    const int IN = 128, HD = 256;
    const int N = in_sizes[0] / IN;
    const int E = in_sizes[1];

    float* out_final = (float*)d_out;          // [N]
    float* h2        = (float*)d_out + N;      // [N,256] (returned h)

    char* ws = (char*)d_ws;
    size_t off = 0;
    auto alloc = [&](size_t bytes) { void* p = ws + off; off += (bytes + 255) & ~255ULL; return p; };
    float* featA  = (float*)alloc((size_t)N * HD * 4);
    float* h1     = (float*)alloc((size_t)N * HD * 4);
    float* el     = (float*)alloc((size_t)N * 2 * 4);
    float* er     = (float*)alloc((size_t)N * 2 * 4);
    float* feat2  = (float*)alloc((size_t)N * 4);
    int*   counts = (int*)alloc((size_t)N * 4);
    int*   cursor = (int*)alloc((size_t)N * 4);
    int*   offs   = (int*)alloc((size_t)(N + 1) * 4);
    int*   csr_src = (int*)alloc((size_t)E * 4);

    hipMemsetAsync(counts, 0, (size_t)N * 4, stream);
    hipMemsetAsync(cursor, 0, (size_t)N * 4, stream);

    count_edges<<<(E + 255) / 256, 256, 0, stream>>>(dst, counts, E);
    scan_offsets<<<1, 1024, 0, stream>>>(counts, offs, N);
    scatter_edges<<<(E + 255) / 256, 256, 0, stream>>>(src, dst, offs, cursor, csr_src, E);

    dim3 gemm_grid((N + 63) / 64, HD / 64);

    // layer 0
    gemm_tiled<<<gemm_grid, 256, 0, stream>>>(features, W0, featA, N, IN, HD);
    compute_eler<<<(N + 1) / 2, 256, 0, stream>>>(featA, al0, ar0, el, er, N);
    gat_aggregate<<<N, 256, 0, stream>>>(featA, el, er, offs, csr_src, b0, h1, N, 1);

    // layer 1 (output h2 goes straight into d_out+N)
    gemm_tiled<<<gemm_grid, 256, 0, stream>>>(h1, W1, featA, N, HD, HD);
    compute_eler<<<(N + 1) / 2, 256, 0, stream>>>(featA, al1, ar1, el, er, N);
    gat_aggregate<<<N, 256, 0, stream>>>(featA, el, er, offs, csr_src, b1, h2, N, 1);

    // layer 2 (scalar head)
    gemv2<<<(N + 3) / 4, 256, 0, stream>>>(h2, W2, feat2, N);
    gat_aggregate2<<<(N + 255) / 256, 256, 0, stream>>>(feat2, al2, ar2, b2, offs, csr_src, out_final, N);
}